// Round 2
// baseline (760.071 us; speedup 1.0000x reference)
//
#include <hip/hip_runtime.h>

typedef unsigned short ushort_t;
typedef __attribute__((ext_vector_type(8))) __bf16 bf16x8;
typedef __attribute__((ext_vector_type(4))) float floatx4;

#define TOKS 100352   // 32*56*56

// ---------- helpers ----------
__device__ __forceinline__ ushort_t f2bf(float f) {
    union { float f; unsigned u; } a; a.f = f;
    unsigned r = a.u + 0x7fffu + ((a.u >> 16) & 1u);   // RNE
    return (ushort_t)(r >> 16);
}

__device__ __forceinline__ void async16(const void* g, void* l) {
    __builtin_amdgcn_global_load_lds(
        (const __attribute__((address_space(1))) unsigned int*)g,
        (__attribute__((address_space(3))) unsigned int*)l,
        16, 0, 0);
}

// window-layout token -> original token (shift +3 both axes). Bijection.
__device__ __forceinline__ int win_to_orig(int t) {
    int b = t / 3136, rr = t - b * 3136;
    int w_ = rr / 49, pos = rr - w_ * 49;
    int wi = w_ >> 3, wj = w_ & 7;
    int ti = pos / 7, tj = pos - ti * 7;
    int h = wi * 7 + ti + 3; if (h >= 56) h -= 56;
    int w = wj * 7 + tj + 3; if (w >= 56) w -= 56;
    return b * 3136 + h * 56 + w;
}

// ---------- weight convert + fused (rel-pos bias + shift mask) table ----------
// bm[wimg][head][i*49+j] = rpb[rel_idx[ij]][head] + mask[wimg][ij]   (fp32, in d_out scratch)
__global__ void convert_kernel(const float* __restrict__ qkv_w, const float* __restrict__ proj_w,
                               const float* __restrict__ fc1_w, const float* __restrict__ fc2_w,
                               const float* __restrict__ rpb, const int* __restrict__ rel_idx,
                               const float* __restrict__ amask,
                               ushort_t* __restrict__ wq, ushort_t* __restrict__ wp,
                               ushort_t* __restrict__ w1, ushort_t* __restrict__ w2,
                               float* __restrict__ bm) {
    int i = blockIdx.x * 256 + threadIdx.x;        // grid covers 1,229,568
    if (i < 196608) wq[i] = f2bf(qkv_w[i]);
    if (i < 65536)  wp[i] = f2bf(proj_w[i]);
    if (i < 262144) { w1[i] = f2bf(fc1_w[i]); w2[i] = f2bf(fc2_w[i]); }
    if (i < 1229312) {                              // 64 wimg * 8 heads * 2401
        int wh = i / 2401, ij = i - wh * 2401;
        int head = wh & 7, wimg = wh >> 3;
        bm[i] = rpb[rel_idx[ij] * 8 + head] + amask[wimg * 2401 + ij];
    }
}

// ---------- LayerNorm (one wave per token, float4 loads) ----------
template <int GATHER>
__global__ __launch_bounds__(256) void ln_kernel(const float* __restrict__ xin,
                                                 const float* __restrict__ gw,
                                                 const float* __restrict__ gb,
                                                 ushort_t* __restrict__ outb) {
    const int wid = threadIdx.x >> 6, lane = threadIdx.x & 63;
    const int t_out = blockIdx.x * 4 + wid;
    const int t_in = GATHER ? win_to_orig(t_out) : t_out;
    const float4* src = (const float4*)(xin + (long)t_in * 256);
    float4 v = src[lane];
    float s  = v.x + v.y + v.z + v.w;
    float s2 = v.x*v.x + v.y*v.y + v.z*v.z + v.w*v.w;
    #pragma unroll
    for (int d = 32; d >= 1; d >>= 1) { s += __shfl_xor(s, d, 64); s2 += __shfl_xor(s2, d, 64); }
    float mu  = s * 0.00390625f;
    float var = s2 * 0.00390625f - mu * mu;
    float ry  = rsqrtf(var + 1e-5f);
    float4 w4 = ((const float4*)gw)[lane], b4 = ((const float4*)gb)[lane];
    unsigned long long p =
          (unsigned long long)f2bf((v.x - mu) * ry * w4.x + b4.x)
        | ((unsigned long long)f2bf((v.y - mu) * ry * w4.y + b4.y) << 16)
        | ((unsigned long long)f2bf((v.z - mu) * ry * w4.z + b4.z) << 32)
        | ((unsigned long long)f2bf((v.w - mu) * ry * w4.w + b4.w) << 48);
    ((unsigned long long*)(outb + (long)t_out * 256))[lane] = p;
}

// ---------- 128x128 MFMA GEMM (m97 structure) ----------
// MODE 0: out bf16 = acc + bias          (QKV)
// MODE 2: out bf16 = gelu(acc + bias)    (fc1)
// MODE 3: out fp32 += acc + bias         (fc2 += into d_out)
template <int MODE, int N_LD, int KD>
__global__ __launch_bounds__(256, 2) void gemm_kernel(const ushort_t* __restrict__ A,
                                                      const ushort_t* __restrict__ Bw,
                                                      const float* __restrict__ bias,
                                                      void* __restrict__ outp) {
    __shared__ __align__(16) ushort_t As[128 * 32];
    __shared__ __align__(16) ushort_t Bs[128 * 32];
    const int tid = threadIdx.x;
    const int lane = tid & 63;
    const int wid = tid >> 6;
    const int wm = wid & 1, wn = wid >> 1;
    const int l15 = lane & 15, quad = lane >> 4;
    const long tileM = (long)blockIdx.y * 128;
    const long tileN = (long)blockIdx.x * 128;

    floatx4 acc[4][4];
    #pragma unroll
    for (int i = 0; i < 4; i++)
        #pragma unroll
        for (int j = 0; j < 4; j++) acc[i][j] = {0.f, 0.f, 0.f, 0.f};

    const int o1 = tid * 16;
    const int r1 = o1 >> 6, c1 = (o1 & 63) >> 1;
    const ushort_t* Ar1 = A + (tileM + r1) * KD + c1;
    const ushort_t* Ar2 = A + (tileM + r1 + 64) * KD + c1;
    const ushort_t* Br1 = Bw + (tileN + r1) * KD + c1;
    const ushort_t* Br2 = Bw + (tileN + r1 + 64) * KD + c1;
    ushort_t* Ad1 = &As[o1 >> 1];
    ushort_t* Ad2 = &As[(o1 >> 1) + 2048];
    ushort_t* Bd1 = &Bs[o1 >> 1];
    ushort_t* Bd2 = &Bs[(o1 >> 1) + 2048];

    for (int k0 = 0; k0 < KD; k0 += 32) {
        async16(Ar1 + k0, Ad1);
        async16(Ar2 + k0, Ad2);
        async16(Br1 + k0, Bd1);
        async16(Br2 + k0, Bd2);
        __syncthreads();
        bf16x8 af[4], bfr[4];
        #pragma unroll
        for (int mi = 0; mi < 4; mi++)
            af[mi] = *(const bf16x8*)&As[(wm * 64 + mi * 16 + l15) * 32 + quad * 8];
        #pragma unroll
        for (int nj = 0; nj < 4; nj++)
            bfr[nj] = *(const bf16x8*)&Bs[(wn * 64 + nj * 16 + l15) * 32 + quad * 8];
        #pragma unroll
        for (int mi = 0; mi < 4; mi++)
            #pragma unroll
            for (int nj = 0; nj < 4; nj++)
                acc[mi][nj] = __builtin_amdgcn_mfma_f32_16x16x32_bf16(af[mi], bfr[nj], acc[mi][nj], 0, 0, 0);
        __syncthreads();
    }

    #pragma unroll
    for (int mi = 0; mi < 4; mi++)
      #pragma unroll
      for (int nj = 0; nj < 4; nj++)
        #pragma unroll
        for (int r = 0; r < 4; r++) {
            long row = tileM + wm * 64 + mi * 16 + quad * 4 + r;
            long col = tileN + wn * 64 + nj * 16 + l15;
            float v = acc[mi][nj][r] + bias[col];
            if (MODE == 0) {
                ((ushort_t*)outp)[row * N_LD + col] = f2bf(v);
            } else if (MODE == 2) {
                float g = 0.5f * v * (1.f + erff(v * 0.70710678118654752f));
                ((ushort_t*)outp)[row * N_LD + col] = f2bf(g);
            } else {
                ((float*)outp)[row * N_LD + col] += v;
            }
        }
}

// ---------- proj GEMM + window-reverse scatter + residual + LN2 (fused) ----------
// block: 64 rows x 256 cols (full DIM), 4 waves (wave = 64-col slice)
__global__ __launch_bounds__(256, 2) void proj_ln_kernel(
        const ushort_t* __restrict__ A, const ushort_t* __restrict__ Bw,
        const float* __restrict__ pb, const float* __restrict__ x_res,
        const float* __restrict__ n2w, const float* __restrict__ n2b,
        float* __restrict__ xout, ushort_t* __restrict__ h2out) {
    __shared__ __align__(16) ushort_t As[64 * 32];     // 4 KB
    __shared__ __align__(16) ushort_t Bs[256 * 32];    // 16 KB
    __shared__ float red_s[4][64];
    __shared__ float red_q[4][64];
    const int tid = threadIdx.x, lane = tid & 63, wid = tid >> 6;
    const int l15 = lane & 15, quad = lane >> 4;
    const long tileM = (long)blockIdx.x * 64;

    floatx4 acc[4][4];
    #pragma unroll
    for (int i = 0; i < 4; i++)
        #pragma unroll
        for (int j = 0; j < 4; j++) acc[i][j] = {0.f, 0.f, 0.f, 0.f};

    const int oA = tid * 16;
    const int rA = oA >> 6, cA = (oA & 63) >> 1;
    const ushort_t* Ap = A + (tileM + rA) * 256 + cA;
    ushort_t* Ad = &As[oA >> 1];

    for (int k0 = 0; k0 < 256; k0 += 32) {
        async16(Ap + k0, Ad);
        #pragma unroll
        for (int ch = 0; ch < 4; ch++) {
            int o = ch * 4096 + oA;
            async16(Bw + (o >> 6) * 256 + ((o & 63) >> 1) + k0, &Bs[o >> 1]);
        }
        __syncthreads();
        bf16x8 af[4], bfr[4];
        #pragma unroll
        for (int mi = 0; mi < 4; mi++)
            af[mi] = *(const bf16x8*)&As[(mi * 16 + l15) * 32 + quad * 8];
        #pragma unroll
        for (int nj = 0; nj < 4; nj++)
            bfr[nj] = *(const bf16x8*)&Bs[(wid * 64 + nj * 16 + l15) * 32 + quad * 8];
        #pragma unroll
        for (int mi = 0; mi < 4; mi++)
            #pragma unroll
            for (int nj = 0; nj < 4; nj++)
                acc[mi][nj] = __builtin_amdgcn_mfma_f32_16x16x32_bf16(af[mi], bfr[nj], acc[mi][nj], 0, 0, 0);
        __syncthreads();
    }

    // epilogue pass 1: x1 = acc + bias + residual (scatter to orig), row partial sums
    int orig[4][4];
    #pragma unroll
    for (int mi = 0; mi < 4; mi++)
      #pragma unroll
      for (int r = 0; r < 4; r++) {
        int iloc = mi * 16 + quad * 4 + r;
        orig[mi][r] = win_to_orig((int)tileM + iloc);
        float s = 0.f, q = 0.f;
        #pragma unroll
        for (int nj = 0; nj < 4; nj++) {
            int col = wid * 64 + nj * 16 + l15;
            long gi = (long)orig[mi][r] * 256 + col;
            float v = acc[mi][nj][r] + pb[col] + x_res[gi];
            xout[gi] = v;
            acc[mi][nj][r] = v;
            s += v; q += v * v;
        }
        #pragma unroll
        for (int d = 1; d < 16; d <<= 1) { s += __shfl_xor(s, d, 64); q += __shfl_xor(q, d, 64); }
        if (l15 == 0) { red_s[wid][iloc] = s; red_q[wid][iloc] = q; }
      }
    __syncthreads();
    // epilogue pass 2: LN over 256 cols -> h2 (bf16)
    #pragma unroll
    for (int mi = 0; mi < 4; mi++)
      #pragma unroll
      for (int r = 0; r < 4; r++) {
        int iloc = mi * 16 + quad * 4 + r;
        float s = red_s[0][iloc] + red_s[1][iloc] + red_s[2][iloc] + red_s[3][iloc];
        float q = red_q[0][iloc] + red_q[1][iloc] + red_q[2][iloc] + red_q[3][iloc];
        float mu = s * 0.00390625f;
        float var = q * 0.00390625f - mu * mu;
        float rstd = rsqrtf(var + 1e-5f);
        #pragma unroll
        for (int nj = 0; nj < 4; nj++) {
            int col = wid * 64 + nj * 16 + l15;
            float v = acc[mi][nj][r];
            h2out[(long)orig[mi][r] * 256 + col] = f2bf((v - mu) * rstd * n2w[col] + n2b[col]);
        }
      }
}

// ---------- attention: ONE WAVE per (window, head); 49 padded to 64 ----------
__global__ __launch_bounds__(64) void attn_kernel(const ushort_t* __restrict__ qkv,
                                                  const float* __restrict__ bm,
                                                  ushort_t* __restrict__ attnout) {
    __shared__ __align__(16) ushort_t lds[96 * 72];    // P[64][72] + Vt[32][72] = 13824 B
    ushort_t* Pl = lds;
    ushort_t* Vt = lds + 64 * 72;
    const int lane = threadIdx.x;
    const int whid = blockIdx.x;                       // 16384 window-heads
    const int win = whid >> 3, head = whid & 7;
    const int l15 = lane & 15, quad = lane >> 4;
    const long base = (long)win * 49 * 768;
    const float* bmw = bm + (long)((win & 63) * 8 + head) * 2401;

    // Q (A-frag) and K (B-frag) straight from global
    bf16x8 qf[4], kf[4];
    #pragma unroll
    for (int t4 = 0; t4 < 4; t4++) {
        int tok = t4 * 16 + l15; if (tok > 48) tok = 48;
        const ushort_t* p = qkv + base + (long)tok * 768 + head * 32 + quad * 8;
        qf[t4] = *(const bf16x8*)p;
        kf[t4] = *(const bf16x8*)(p + 256);
    }

    floatx4 S[4][4];
    #pragma unroll
    for (int mi = 0; mi < 4; mi++)
        #pragma unroll
        for (int nj = 0; nj < 4; nj++) {
            floatx4 z = {0.f, 0.f, 0.f, 0.f};
            S[mi][nj] = __builtin_amdgcn_mfma_f32_16x16x32_bf16(qf[mi], kf[nj], z, 0, 0, 0);
        }

    // stage V^T into LDS (stride 72), zero-fill pad cols j>=49
    {
        int j = lane;
        int jc = j < 49 ? j : 48;
        const uint4* vsrc = (const uint4*)(qkv + base + (long)jc * 768 + 512 + head * 32);
        uint4 vz; vz.x = vz.y = vz.z = vz.w = 0u;
        #pragma unroll
        for (int q4 = 0; q4 < 4; q4++) {
            uint4 vv = (j < 49) ? vsrc[q4] : vz;
            int db = q4 * 8;
            Vt[(db+0)*72 + j] = (ushort_t)vv.x;  Vt[(db+1)*72 + j] = (ushort_t)(vv.x >> 16);
            Vt[(db+2)*72 + j] = (ushort_t)vv.y;  Vt[(db+3)*72 + j] = (ushort_t)(vv.y >> 16);
            Vt[(db+4)*72 + j] = (ushort_t)vv.z;  Vt[(db+5)*72 + j] = (ushort_t)(vv.z >> 16);
            Vt[(db+6)*72 + j] = (ushort_t)vv.w;  Vt[(db+7)*72 + j] = (ushort_t)(vv.w >> 16);
        }
    }

    // scale + fused bias/mask; pad -1e30
    const float scale = 0.17677669529663687f;          // 32^-0.5
    #pragma unroll
    for (int mi = 0; mi < 4; mi++)
      #pragma unroll
      for (int nj = 0; nj < 4; nj++)
        #pragma unroll
        for (int r = 0; r < 4; r++) {
            int i = mi * 16 + quad * 4 + r;
            int j = nj * 16 + l15;
            float s = -1e30f;
            if (i < 49 && j < 49) s = S[mi][nj][r] * scale + bmw[i * 49 + j];
            S[mi][nj][r] = s;
        }

    // row softmax (unnormalized into P; 1/sum folded into epilogue)
    float rinv[4][4];
    #pragma unroll
    for (int mi = 0; mi < 4; mi++)
      #pragma unroll
      for (int r = 0; r < 4; r++) {
          float m = fmaxf(fmaxf(S[mi][0][r], S[mi][1][r]), fmaxf(S[mi][2][r], S[mi][3][r]));
          #pragma unroll
          for (int d = 1; d < 16; d <<= 1) m = fmaxf(m, __shfl_xor(m, d, 64));
          float e[4], sum = 0.f;
          #pragma unroll
          for (int nj = 0; nj < 4; nj++) { e[nj] = __expf(S[mi][nj][r] - m); sum += e[nj]; }
          #pragma unroll
          for (int d = 1; d < 16; d <<= 1) sum += __shfl_xor(sum, d, 64);
          rinv[mi][r] = 1.f / sum;
          int i = mi * 16 + quad * 4 + r;
          #pragma unroll
          for (int nj = 0; nj < 4; nj++) Pl[i * 72 + (nj * 16 + l15)] = f2bf(e[nj]);
      }

    __syncthreads();   // single wave: cheap; orders LDS writes before frag reads

    floatx4 O[4][2];
    #pragma unroll
    for (int mi = 0; mi < 4; mi++) { O[mi][0] = {0.f,0.f,0.f,0.f}; O[mi][1] = {0.f,0.f,0.f,0.f}; }
    #pragma unroll
    for (int kc = 0; kc < 2; kc++) {
        bf16x8 pf[4], vf[2];
        #pragma unroll
        for (int mi = 0; mi < 4; mi++)
            pf[mi] = *(const bf16x8*)&Pl[(mi * 16 + l15) * 72 + kc * 32 + quad * 8];
        #pragma unroll
        for (int n2 = 0; n2 < 2; n2++)
            vf[n2] = *(const bf16x8*)&Vt[(n2 * 16 + l15) * 72 + kc * 32 + quad * 8];
        #pragma unroll
        for (int mi = 0; mi < 4; mi++)
            #pragma unroll
            for (int n2 = 0; n2 < 2; n2++)
                O[mi][n2] = __builtin_amdgcn_mfma_f32_16x16x32_bf16(pf[mi], vf[n2], O[mi][n2], 0, 0, 0);
    }

    #pragma unroll
    for (int mi = 0; mi < 4; mi++)
      #pragma unroll
      for (int n2 = 0; n2 < 2; n2++)
        #pragma unroll
        for (int r = 0; r < 4; r++) {
            int i = mi * 16 + quad * 4 + r;
            if (i < 49) {
                long orow = ((long)win * 49 + i) * 256 + head * 32 + n2 * 16 + l15;
                attnout[orow] = f2bf(O[mi][n2][r] * rinv[mi][r]);
            }
        }
}

// ---------- launcher ----------
extern "C" void kernel_launch(void* const* d_in, const int* in_sizes, int n_in,
                              void* d_out, int out_size, void* d_ws, size_t ws_size,
                              hipStream_t stream) {
    const float* x      = (const float*)d_in[0];
    const float* n1w    = (const float*)d_in[1];
    const float* n1b    = (const float*)d_in[2];
    const float* qkv_w  = (const float*)d_in[3];
    const float* qkv_b  = (const float*)d_in[4];
    const float* rpb    = (const float*)d_in[5];
    const float* proj_w = (const float*)d_in[6];
    const float* proj_b = (const float*)d_in[7];
    const float* n2w    = (const float*)d_in[8];
    const float* n2b    = (const float*)d_in[9];
    const float* fc1_w  = (const float*)d_in[10];
    const float* fc1_b  = (const float*)d_in[11];
    const float* fc2_w  = (const float*)d_in[12];
    const float* fc2_b  = (const float*)d_in[13];
    const int*   rel_idx= (const int*)d_in[14];
    const float* amask  = (const float*)d_in[15];

    // ws layout (peak 207.09 MB):
    char* ws = (char*)d_ws;
    ushort_t* wq   = (ushort_t*)(ws + 0);          //  393,216 B
    ushort_t* wp   = (ushort_t*)(ws + 393216);     //  131,072 B
    ushort_t* w1   = (ushort_t*)(ws + 524288);     //  524,288 B
    ushort_t* w2   = (ushort_t*)(ws + 1048576);    //  524,288 B
    ushort_t* hwin = (ushort_t*)(ws + 1572864);    // 51,380,224 B (LN1 out; reused attn_out)
    ushort_t* qkvb = (ushort_t*)(ws + 52953088);   // 154,140,672 B (qkv; reused h2+h3)
    ushort_t* h2   = qkvb;                         // 51,380,224 B
    ushort_t* h3   = (ushort_t*)(ws + 104333312);  // 102,760,448 B
    // bm lives in d_out (dead until proj_ln overwrites it): 4,917,248 B
    float* bm = (float*)d_out;

    convert_kernel<<<4803, 256, 0, stream>>>(qkv_w, proj_w, fc1_w, fc2_w, rpb, rel_idx,
                                             amask, wq, wp, w1, w2, bm);
    ln_kernel<1><<<TOKS / 4, 256, 0, stream>>>(x, n1w, n1b, hwin);
    gemm_kernel<0, 768, 256><<<dim3(6, 784), 256, 0, stream>>>(hwin, wq, qkv_b, qkvb);
    attn_kernel<<<16384, 64, 0, stream>>>(qkvb, bm, hwin);
    proj_ln_kernel<<<1568, 256, 0, stream>>>(hwin, wp, proj_b, x, n2w, n2b, (float*)d_out, h2);
    for (int c = 0; c < 2; c++) {
        gemm_kernel<2, 1024, 256><<<dim3(8, 392), 256, 0, stream>>>(
            h2 + (long)c * 50176 * 256, w1, fc1_b, h3);
        gemm_kernel<3, 256, 1024><<<dim3(2, 392), 256, 0, stream>>>(
            h3, w2, fc2_b, (float*)d_out + (long)c * 50176 * 256);
    }
    (void)in_sizes; (void)n_in; (void)out_size; (void)ws_size;
}

// Round 3
// 750.745 us; speedup vs baseline: 1.0124x; 1.0124x over previous
//
#include <hip/hip_runtime.h>

typedef unsigned short ushort_t;
typedef __attribute__((ext_vector_type(8))) __bf16 bf16x8;
typedef __attribute__((ext_vector_type(4))) float floatx4;

#define TOKS 100352   // 32*56*56

// ---------- helpers ----------
__device__ __forceinline__ ushort_t f2bf(float f) {
    union { float f; unsigned u; } a; a.f = f;
    unsigned r = a.u + 0x7fffu + ((a.u >> 16) & 1u);   // RNE
    return (ushort_t)(r >> 16);
}

__device__ __forceinline__ void async16(const void* g, void* l) {
    __builtin_amdgcn_global_load_lds(
        (const __attribute__((address_space(1))) unsigned int*)g,
        (__attribute__((address_space(3))) unsigned int*)l,
        16, 0, 0);
}

// window-layout token -> original token (shift +3 both axes). Bijection.
__device__ __forceinline__ int win_to_orig(int t) {
    int b = t / 3136, rr = t - b * 3136;
    int w_ = rr / 49, pos = rr - w_ * 49;
    int wi = w_ >> 3, wj = w_ & 7;
    int ti = pos / 7, tj = pos - ti * 7;
    int h = wi * 7 + ti + 3; if (h >= 56) h -= 56;
    int w = wj * 7 + tj + 3; if (w >= 56) w -= 56;
    return b * 3136 + h * 56 + w;
}

// ---------- weight convert + rel-pos bias gather (bias_h[head][2401], 77 KB) ----------
__global__ void convert_kernel(const float* __restrict__ qkv_w, const float* __restrict__ proj_w,
                               const float* __restrict__ fc1_w, const float* __restrict__ fc2_w,
                               const float* __restrict__ rpb, const int* __restrict__ rel_idx,
                               ushort_t* __restrict__ wq, ushort_t* __restrict__ wp,
                               ushort_t* __restrict__ w1, ushort_t* __restrict__ w2,
                               float* __restrict__ bias_h) {
    int i = blockIdx.x * 256 + threadIdx.x;        // grid covers 262144
    if (i < 196608) wq[i] = f2bf(qkv_w[i]);
    if (i < 65536)  wp[i] = f2bf(proj_w[i]);
    if (i < 262144) { w1[i] = f2bf(fc1_w[i]); w2[i] = f2bf(fc2_w[i]); }
    if (i < 19208) {                               // 8 heads * 2401
        int h = i / 2401, ij = i - h * 2401;
        bias_h[i] = rpb[rel_idx[ij] * 8 + h];
    }
}

// ---------- LN1 fused with shift + window-partition gather ----------
__global__ __launch_bounds__(256) void ln_kernel(const float* __restrict__ xin,
                                                 const float* __restrict__ gw,
                                                 const float* __restrict__ gb,
                                                 ushort_t* __restrict__ outb) {
    const int wid = threadIdx.x >> 6, lane = threadIdx.x & 63;
    const int t_out = blockIdx.x * 4 + wid;
    const int t_in = win_to_orig(t_out);
    const float4* src = (const float4*)(xin + (long)t_in * 256);
    float4 v = src[lane];
    float s  = v.x + v.y + v.z + v.w;
    float s2 = v.x*v.x + v.y*v.y + v.z*v.z + v.w*v.w;
    #pragma unroll
    for (int d = 32; d >= 1; d >>= 1) { s += __shfl_xor(s, d, 64); s2 += __shfl_xor(s2, d, 64); }
    float mu  = s * 0.00390625f;
    float var = s2 * 0.00390625f - mu * mu;
    float ry  = rsqrtf(var + 1e-5f);
    float4 w4 = ((const float4*)gw)[lane], b4 = ((const float4*)gb)[lane];
    unsigned long long p =
          (unsigned long long)f2bf((v.x - mu) * ry * w4.x + b4.x)
        | ((unsigned long long)f2bf((v.y - mu) * ry * w4.y + b4.y) << 16)
        | ((unsigned long long)f2bf((v.z - mu) * ry * w4.z + b4.z) << 32)
        | ((unsigned long long)f2bf((v.w - mu) * ry * w4.w + b4.w) << 48);
    ((unsigned long long*)(outb + (long)t_out * 256))[lane] = p;
}

// ---------- 128x128 MFMA GEMM (m97 structure) ----------
// MODE 0: out bf16 = acc + bias                                  (QKV)
// MODE 2: out bf16 = gelu(acc + bias)                            (fc1)
// MODE 4: out fp32 scatter win->orig = acc + bias + x1w[row]     (fc2, final)
template <int MODE, int N_LD, int KD>
__global__ __launch_bounds__(256, 2) void gemm_kernel(const ushort_t* __restrict__ A,
                                                      const ushort_t* __restrict__ Bw,
                                                      const float* __restrict__ bias,
                                                      void* __restrict__ outp,
                                                      const ushort_t* __restrict__ x1w,
                                                      int rowOff) {
    __shared__ __align__(16) ushort_t As[128 * 32];
    __shared__ __align__(16) ushort_t Bs[128 * 32];
    const int tid = threadIdx.x;
    const int lane = tid & 63;
    const int wid = tid >> 6;
    const int wm = wid & 1, wn = wid >> 1;
    const int l15 = lane & 15, quad = lane >> 4;
    const long tileM = (long)blockIdx.y * 128;
    const long tileN = (long)blockIdx.x * 128;

    floatx4 acc[4][4];
    #pragma unroll
    for (int i = 0; i < 4; i++)
        #pragma unroll
        for (int j = 0; j < 4; j++) acc[i][j] = {0.f, 0.f, 0.f, 0.f};

    const int o1 = tid * 16;
    const int r1 = o1 >> 6, c1 = (o1 & 63) >> 1;
    const ushort_t* Ar1 = A + (tileM + r1) * KD + c1;
    const ushort_t* Ar2 = A + (tileM + r1 + 64) * KD + c1;
    const ushort_t* Br1 = Bw + (tileN + r1) * KD + c1;
    const ushort_t* Br2 = Bw + (tileN + r1 + 64) * KD + c1;
    ushort_t* Ad1 = &As[o1 >> 1];
    ushort_t* Ad2 = &As[(o1 >> 1) + 2048];
    ushort_t* Bd1 = &Bs[o1 >> 1];
    ushort_t* Bd2 = &Bs[(o1 >> 1) + 2048];

    for (int k0 = 0; k0 < KD; k0 += 32) {
        async16(Ar1 + k0, Ad1);
        async16(Ar2 + k0, Ad2);
        async16(Br1 + k0, Bd1);
        async16(Br2 + k0, Bd2);
        __syncthreads();
        bf16x8 af[4], bfr[4];
        #pragma unroll
        for (int mi = 0; mi < 4; mi++)
            af[mi] = *(const bf16x8*)&As[(wm * 64 + mi * 16 + l15) * 32 + quad * 8];
        #pragma unroll
        for (int nj = 0; nj < 4; nj++)
            bfr[nj] = *(const bf16x8*)&Bs[(wn * 64 + nj * 16 + l15) * 32 + quad * 8];
        #pragma unroll
        for (int mi = 0; mi < 4; mi++)
            #pragma unroll
            for (int nj = 0; nj < 4; nj++)
                acc[mi][nj] = __builtin_amdgcn_mfma_f32_16x16x32_bf16(af[mi], bfr[nj], acc[mi][nj], 0, 0, 0);
        __syncthreads();
    }

    #pragma unroll
    for (int mi = 0; mi < 4; mi++)
      #pragma unroll
      for (int nj = 0; nj < 4; nj++)
        #pragma unroll
        for (int r = 0; r < 4; r++) {
            long row = tileM + wm * 64 + mi * 16 + quad * 4 + r;
            long col = tileN + wn * 64 + nj * 16 + l15;
            float v = acc[mi][nj][r] + bias[col];
            if (MODE == 0) {
                ((ushort_t*)outp)[row * N_LD + col] = f2bf(v);
            } else if (MODE == 2) {
                float g = 0.5f * v * (1.f + erff(v * 0.70710678118654752f));
                ((ushort_t*)outp)[row * N_LD + col] = f2bf(g);
            } else {  // MODE 4
                union { ushort_t u[2]; unsigned v32; float f; } cvt;
                cvt.u[0] = 0; cvt.u[1] = x1w[row * 256 + col];
                float res = cvt.f;
                int orig = win_to_orig((int)row + rowOff);
                ((float*)outp)[(long)orig * 256 + col] = v + res;
            }
        }
}

// ---------- proj GEMM + residual + LN2 (fused, window-linear in & out) ----------
// block: 64 rows x 256 cols (full DIM), 4 waves (wave = 64-col slice)
__global__ __launch_bounds__(256, 2) void proj_ln_kernel(
        const ushort_t* __restrict__ A, const ushort_t* __restrict__ Bw,
        const float* __restrict__ pb, const float* __restrict__ x_res,
        const float* __restrict__ n2w, const float* __restrict__ n2b,
        ushort_t* __restrict__ x1w, ushort_t* __restrict__ h2out) {
    __shared__ __align__(16) ushort_t As[64 * 32];     // 4 KB
    __shared__ __align__(16) ushort_t Bs[256 * 32];    // 16 KB
    __shared__ float red_s[4][64];
    __shared__ float red_q[4][64];
    const int tid = threadIdx.x, lane = tid & 63, wid = tid >> 6;
    const int l15 = lane & 15, quad = lane >> 4;
    const long tileM = (long)blockIdx.x * 64;

    floatx4 acc[4][4];
    #pragma unroll
    for (int i = 0; i < 4; i++)
        #pragma unroll
        for (int j = 0; j < 4; j++) acc[i][j] = {0.f, 0.f, 0.f, 0.f};

    const int oA = tid * 16;
    const int rA = oA >> 6, cA = (oA & 63) >> 1;
    const ushort_t* Ap = A + (tileM + rA) * 256 + cA;
    ushort_t* Ad = &As[oA >> 1];

    for (int k0 = 0; k0 < 256; k0 += 32) {
        async16(Ap + k0, Ad);
        #pragma unroll
        for (int ch = 0; ch < 4; ch++) {
            int o = ch * 4096 + oA;
            async16(Bw + (o >> 6) * 256 + ((o & 63) >> 1) + k0, &Bs[o >> 1]);
        }
        __syncthreads();
        bf16x8 af[4], bfr[4];
        #pragma unroll
        for (int mi = 0; mi < 4; mi++)
            af[mi] = *(const bf16x8*)&As[(mi * 16 + l15) * 32 + quad * 8];
        #pragma unroll
        for (int nj = 0; nj < 4; nj++)
            bfr[nj] = *(const bf16x8*)&Bs[(wid * 64 + nj * 16 + l15) * 32 + quad * 8];
        #pragma unroll
        for (int mi = 0; mi < 4; mi++)
            #pragma unroll
            for (int nj = 0; nj < 4; nj++)
                acc[mi][nj] = __builtin_amdgcn_mfma_f32_16x16x32_bf16(af[mi], bfr[nj], acc[mi][nj], 0, 0, 0);
        __syncthreads();
    }

    // pass 1: x1 = acc + bias + x[orig] (residual gather), partial row sums
    #pragma unroll
    for (int mi = 0; mi < 4; mi++)
      #pragma unroll
      for (int r = 0; r < 4; r++) {
        int iloc = mi * 16 + quad * 4 + r;
        int orig = win_to_orig((int)tileM + iloc);
        float s = 0.f, q = 0.f;
        #pragma unroll
        for (int nj = 0; nj < 4; nj++) {
            int col = wid * 64 + nj * 16 + l15;
            float v = acc[mi][nj][r] + pb[col] + x_res[(long)orig * 256 + col];
            x1w[(tileM + iloc) * 256 + col] = f2bf(v);
            acc[mi][nj][r] = v;
            s += v; q += v * v;
        }
        #pragma unroll
        for (int d = 1; d < 16; d <<= 1) { s += __shfl_xor(s, d, 64); q += __shfl_xor(q, d, 64); }
        if (l15 == 0) { red_s[wid][iloc] = s; red_q[wid][iloc] = q; }
      }
    __syncthreads();
    // pass 2: LN over 256 cols -> h2 (bf16, window-linear)
    #pragma unroll
    for (int mi = 0; mi < 4; mi++)
      #pragma unroll
      for (int r = 0; r < 4; r++) {
        int iloc = mi * 16 + quad * 4 + r;
        float s = red_s[0][iloc] + red_s[1][iloc] + red_s[2][iloc] + red_s[3][iloc];
        float q = red_q[0][iloc] + red_q[1][iloc] + red_q[2][iloc] + red_q[3][iloc];
        float mu = s * 0.00390625f;
        float var = q * 0.00390625f - mu * mu;
        float rstd = rsqrtf(var + 1e-5f);
        #pragma unroll
        for (int nj = 0; nj < 4; nj++) {
            int col = wid * 64 + nj * 16 + l15;
            float v = acc[mi][nj][r];
            h2out[(tileM + iloc) * 256 + col] = f2bf((v - mu) * rstd * n2w[col] + n2b[col]);
        }
      }
}

// ---------- attention: 2 waves/block (2 heads of one window); 49 padded to 64 ----------
__global__ __launch_bounds__(128) void attn_kernel(const ushort_t* __restrict__ qkv,
                                                   const float* __restrict__ bias_h,
                                                   const float* __restrict__ mask,
                                                   ushort_t* __restrict__ attnout) {
    __shared__ __align__(16) ushort_t lds[2 * 6912];   // per wave: P[64][72] + Vt[32][72]
    const int tid = threadIdx.x, lane = tid & 63, wid = tid >> 6;
    ushort_t* Pl = &lds[wid * 6912];
    ushort_t* Vt = Pl + 64 * 72;
    const int whid = blockIdx.x * 2 + wid;             // 16384 window-heads
    const int win = whid >> 3, head = whid & 7;
    const int l15 = lane & 15, quad = lane >> 4;
    const long base = (long)win * 49 * 768;
    const float* bh = bias_h + head * 2401;
    const float* mk = mask + (win & 63) * 2401;

    // Q (A-frag) and K (B-frag) straight from global
    bf16x8 qf[4], kf[4];
    #pragma unroll
    for (int t4 = 0; t4 < 4; t4++) {
        int tok = t4 * 16 + l15; if (tok > 48) tok = 48;
        const ushort_t* p = qkv + base + (long)tok * 768 + head * 32 + quad * 8;
        qf[t4] = *(const bf16x8*)p;
        kf[t4] = *(const bf16x8*)(p + 256);
    }

    floatx4 S[4][4];
    #pragma unroll
    for (int mi = 0; mi < 4; mi++)
        #pragma unroll
        for (int nj = 0; nj < 4; nj++) {
            floatx4 z = {0.f, 0.f, 0.f, 0.f};
            S[mi][nj] = __builtin_amdgcn_mfma_f32_16x16x32_bf16(qf[mi], kf[nj], z, 0, 0, 0);
        }

    // stage V^T into LDS (stride 72), zero-fill pad cols j>=49
    {
        int j = lane;
        int jc = j < 49 ? j : 48;
        const uint4* vsrc = (const uint4*)(qkv + base + (long)jc * 768 + 512 + head * 32);
        uint4 vz; vz.x = vz.y = vz.z = vz.w = 0u;
        #pragma unroll
        for (int q4 = 0; q4 < 4; q4++) {
            uint4 vv = (j < 49) ? vsrc[q4] : vz;
            int db = q4 * 8;
            Vt[(db+0)*72 + j] = (ushort_t)vv.x;  Vt[(db+1)*72 + j] = (ushort_t)(vv.x >> 16);
            Vt[(db+2)*72 + j] = (ushort_t)vv.y;  Vt[(db+3)*72 + j] = (ushort_t)(vv.y >> 16);
            Vt[(db+4)*72 + j] = (ushort_t)vv.z;  Vt[(db+5)*72 + j] = (ushort_t)(vv.z >> 16);
            Vt[(db+6)*72 + j] = (ushort_t)vv.w;  Vt[(db+7)*72 + j] = (ushort_t)(vv.w >> 16);
        }
    }

    // scale + rel-pos bias + shift mask; pad -1e30
    const float scale = 0.17677669529663687f;          // 32^-0.5
    #pragma unroll
    for (int mi = 0; mi < 4; mi++)
      #pragma unroll
      for (int nj = 0; nj < 4; nj++)
        #pragma unroll
        for (int r = 0; r < 4; r++) {
            int i = mi * 16 + quad * 4 + r;
            int j = nj * 16 + l15;
            float s = -1e30f;
            if (i < 49 && j < 49) {
                int ij = i * 49 + j;
                s = S[mi][nj][r] * scale + bh[ij] + mk[ij];
            }
            S[mi][nj][r] = s;
        }

    // row softmax (unnormalized into P; 1/sum folded into output epilogue)
    float rinv[4][4];
    #pragma unroll
    for (int mi = 0; mi < 4; mi++)
      #pragma unroll
      for (int r = 0; r < 4; r++) {
          float m = fmaxf(fmaxf(S[mi][0][r], S[mi][1][r]), fmaxf(S[mi][2][r], S[mi][3][r]));
          #pragma unroll
          for (int d = 1; d < 16; d <<= 1) m = fmaxf(m, __shfl_xor(m, d, 64));
          float e[4], sum = 0.f;
          #pragma unroll
          for (int nj = 0; nj < 4; nj++) { e[nj] = __expf(S[mi][nj][r] - m); sum += e[nj]; }
          #pragma unroll
          for (int d = 1; d < 16; d <<= 1) sum += __shfl_xor(sum, d, 64);
          rinv[mi][r] = 1.f / sum;
          int i = mi * 16 + quad * 4 + r;
          #pragma unroll
          for (int nj = 0; nj < 4; nj++) Pl[i * 72 + (nj * 16 + l15)] = f2bf(e[nj]);
      }

    __syncthreads();

    floatx4 O[4][2];
    #pragma unroll
    for (int mi = 0; mi < 4; mi++) { O[mi][0] = {0.f,0.f,0.f,0.f}; O[mi][1] = {0.f,0.f,0.f,0.f}; }
    #pragma unroll
    for (int kc = 0; kc < 2; kc++) {
        bf16x8 pf[4], vf[2];
        #pragma unroll
        for (int mi = 0; mi < 4; mi++)
            pf[mi] = *(const bf16x8*)&Pl[(mi * 16 + l15) * 72 + kc * 32 + quad * 8];
        #pragma unroll
        for (int n2 = 0; n2 < 2; n2++)
            vf[n2] = *(const bf16x8*)&Vt[(n2 * 16 + l15) * 72 + kc * 32 + quad * 8];
        #pragma unroll
        for (int mi = 0; mi < 4; mi++)
            #pragma unroll
            for (int n2 = 0; n2 < 2; n2++)
                O[mi][n2] = __builtin_amdgcn_mfma_f32_16x16x32_bf16(pf[mi], vf[n2], O[mi][n2], 0, 0, 0);
    }

    #pragma unroll
    for (int mi = 0; mi < 4; mi++)
      #pragma unroll
      for (int n2 = 0; n2 < 2; n2++)
        #pragma unroll
        for (int r = 0; r < 4; r++) {
            int i = mi * 16 + quad * 4 + r;
            if (i < 49) {
                long orow = ((long)win * 49 + i) * 256 + head * 32 + n2 * 16 + l15;
                attnout[orow] = f2bf(O[mi][n2][r] * rinv[mi][r]);
            }
        }
}

// ---------- launcher ----------
extern "C" void kernel_launch(void* const* d_in, const int* in_sizes, int n_in,
                              void* d_out, int out_size, void* d_ws, size_t ws_size,
                              hipStream_t stream) {
    const float* x      = (const float*)d_in[0];
    const float* n1w    = (const float*)d_in[1];
    const float* n1b    = (const float*)d_in[2];
    const float* qkv_w  = (const float*)d_in[3];
    const float* qkv_b  = (const float*)d_in[4];
    const float* rpb    = (const float*)d_in[5];
    const float* proj_w = (const float*)d_in[6];
    const float* proj_b = (const float*)d_in[7];
    const float* n2w    = (const float*)d_in[8];
    const float* n2b    = (const float*)d_in[9];
    const float* fc1_w  = (const float*)d_in[10];
    const float* fc1_b  = (const float*)d_in[11];
    const float* fc2_w  = (const float*)d_in[12];
    const float* fc2_b  = (const float*)d_in[13];
    const int*   rel_idx= (const int*)d_in[14];
    const float* amask  = (const float*)d_in[15];

    // ws layout (peak 207,170,624 B <= 207,224,832 proven in round 1):
    char* ws = (char*)d_ws;
    ushort_t* wq   = (ushort_t*)(ws + 0);          //  393,216 B
    ushort_t* wp   = (ushort_t*)(ws + 393216);     //  131,072 B
    ushort_t* w1   = (ushort_t*)(ws + 524288);     //  524,288 B
    ushort_t* w2   = (ushort_t*)(ws + 1048576);    //  524,288 B
    float*    bh   = (float*)   (ws + 1572864);    //   76,832 B (pad to 1,649,728)
    ushort_t* hwin = (ushort_t*)(ws + 1649728);    // 51,380,224 B (LN1 out; reused attn_out; later h3)
    ushort_t* qkvb = (ushort_t*)(ws + 53029952);   // 154,140,672 B (qkv; reused h2 + x1w)
    ushort_t* h2   = (ushort_t*)(ws + 104410176);  // 51,380,224 B
    ushort_t* x1w  = (ushort_t*)(ws + 155790400);  // 51,380,224 B
    ushort_t* h3   = hwin;                         // 102,760,448 B per half (hwin+attno dead)

    convert_kernel<<<1024, 256, 0, stream>>>(qkv_w, proj_w, fc1_w, fc2_w, rpb, rel_idx,
                                             wq, wp, w1, w2, bh);
    ln_kernel<<<TOKS / 4, 256, 0, stream>>>(x, n1w, n1b, hwin);
    gemm_kernel<0, 768, 256><<<dim3(6, 784), 256, 0, stream>>>(hwin, wq, qkv_b, qkvb, nullptr, 0);
    attn_kernel<<<8192, 128, 0, stream>>>(qkvb, bh, amask, hwin);
    proj_ln_kernel<<<1568, 256, 0, stream>>>(hwin, wp, proj_b, x, n2w, n2b, x1w, h2);
    for (int c = 0; c < 2; c++) {
        gemm_kernel<2, 1024, 256><<<dim3(8, 392), 256, 0, stream>>>(
            h2 + (long)c * 50176 * 256, w1, fc1_b, h3, nullptr, 0);
        gemm_kernel<4, 256, 1024><<<dim3(2, 392), 256, 0, stream>>>(
            h3, w2, fc2_b, (float*)d_out, x1w + (long)c * 50176 * 256, c * 50176);
    }
    (void)in_sizes; (void)n_in; (void)out_size; (void)ws_size;
}

// Round 4
// 658.696 us; speedup vs baseline: 1.1539x; 1.1397x over previous
//
#include <hip/hip_runtime.h>

typedef unsigned short ushort_t;
typedef __attribute__((ext_vector_type(8))) __bf16 bf16x8;
typedef __attribute__((ext_vector_type(4))) float floatx4;

#define TOKS 100352   // 32*56*56

// ---------- helpers ----------
__device__ __forceinline__ ushort_t f2bf(float f) {
    union { float f; unsigned u; } a; a.f = f;
    unsigned r = a.u + 0x7fffu + ((a.u >> 16) & 1u);   // RNE
    return (ushort_t)(r >> 16);
}
__device__ __forceinline__ float bf2f(ushort_t u) {
    union { unsigned v; float f; } a; a.v = ((unsigned)u) << 16; return a.f;
}

__device__ __forceinline__ void async16(const void* g, void* l) {
    __builtin_amdgcn_global_load_lds(
        (const __attribute__((address_space(1))) unsigned int*)g,
        (__attribute__((address_space(3))) unsigned int*)l,
        16, 0, 0);
}

// window-layout token -> original token (shift +3 both axes). Bijection.
__device__ __forceinline__ int win_to_orig(int t) {
    int b = t / 3136, rr = t - b * 3136;
    int w_ = rr / 49, pos = rr - w_ * 49;
    int wi = w_ >> 3, wj = w_ & 7;
    int ti = pos / 7, tj = pos - ti * 7;
    int h = wi * 7 + ti + 3; if (h >= 56) h -= 56;
    int w = wj * 7 + tj + 3; if (w >= 56) w -= 56;
    return b * 3136 + h * 56 + w;
}

// ---------- weight convert + fused (bias+mask) bf16 table ----------
// bm[wimg][head][ij] = bf16( rpb[rel_idx[ij]][head] + mask[wimg][ij] )  -- 2.45 MB, L2-resident
__global__ void convert_kernel(const float* __restrict__ qkv_w, const float* __restrict__ proj_w,
                               const float* __restrict__ fc1_w, const float* __restrict__ fc2_w,
                               const float* __restrict__ rpb, const int* __restrict__ rel_idx,
                               const float* __restrict__ amask,
                               ushort_t* __restrict__ wq, ushort_t* __restrict__ wp,
                               ushort_t* __restrict__ w1, ushort_t* __restrict__ w2,
                               ushort_t* __restrict__ bm) {
    int i = blockIdx.x * 256 + threadIdx.x;        // grid covers 1,229,568
    if (i < 196608) wq[i] = f2bf(qkv_w[i]);
    if (i < 65536)  wp[i] = f2bf(proj_w[i]);
    if (i < 262144) { w1[i] = f2bf(fc1_w[i]); w2[i] = f2bf(fc2_w[i]); }
    if (i < 1229312) {                              // 64 wimg * 8 heads * 2401
        int wh = i / 2401, ij = i - wh * 2401;
        int head = wh & 7, wimg = wh >> 3;
        bm[i] = f2bf(rpb[rel_idx[ij] * 8 + head] + amask[wimg * 2401 + ij]);
    }
}

// ---------- LN1 fused with shift + window-partition gather ----------
__global__ __launch_bounds__(256) void ln_kernel(const float* __restrict__ xin,
                                                 const float* __restrict__ gw,
                                                 const float* __restrict__ gb,
                                                 ushort_t* __restrict__ outb) {
    const int wid = threadIdx.x >> 6, lane = threadIdx.x & 63;
    const int t_out = blockIdx.x * 4 + wid;
    const int t_in = win_to_orig(t_out);
    const float4* src = (const float4*)(xin + (long)t_in * 256);
    float4 v = src[lane];
    float s  = v.x + v.y + v.z + v.w;
    float s2 = v.x*v.x + v.y*v.y + v.z*v.z + v.w*v.w;
    #pragma unroll
    for (int d = 32; d >= 1; d >>= 1) { s += __shfl_xor(s, d, 64); s2 += __shfl_xor(s2, d, 64); }
    float mu  = s * 0.00390625f;
    float var = s2 * 0.00390625f - mu * mu;
    float ry  = rsqrtf(var + 1e-5f);
    float4 w4 = ((const float4*)gw)[lane], b4 = ((const float4*)gb)[lane];
    unsigned long long p =
          (unsigned long long)f2bf((v.x - mu) * ry * w4.x + b4.x)
        | ((unsigned long long)f2bf((v.y - mu) * ry * w4.y + b4.y) << 16)
        | ((unsigned long long)f2bf((v.z - mu) * ry * w4.z + b4.z) << 32)
        | ((unsigned long long)f2bf((v.w - mu) * ry * w4.w + b4.w) << 48);
    ((unsigned long long*)(outb + (long)t_out * 256))[lane] = p;
}

// ---------- 128x128 MFMA GEMM, XCD-swizzled 1-D grid ----------
// grid.x = RT*CT, RT multiple of 8. v=blockIdx.x: xcd=v&7, col=(v>>3)%CT,
// band=(v>>3)/CT, row=band*8+xcd  -> all CT col-tiles of a band co-run on one XCD,
// so the A row-band is fetched from HBM once and re-read from that XCD's L2.
// MODE 0: out bf16 = acc + bias                                  (QKV)
// MODE 2: out bf16 = gelu(acc + bias)                            (fc1)
// MODE 4: out fp32 scatter win->orig = acc + bias + x1w[row]     (fc2, final)
template <int MODE, int N_LD, int KD, int CT>
__global__ __launch_bounds__(256, 2) void gemm_kernel(const ushort_t* __restrict__ A,
                                                      const ushort_t* __restrict__ Bw,
                                                      const float* __restrict__ bias,
                                                      void* __restrict__ outp,
                                                      const ushort_t* __restrict__ x1w,
                                                      int rowOff) {
    __shared__ __align__(16) ushort_t As[128 * 32];
    __shared__ __align__(16) ushort_t Bs[128 * 32];
    const int tid = threadIdx.x;
    const int lane = tid & 63;
    const int wid = tid >> 6;
    const int wm = wid & 1, wn = wid >> 1;
    const int l15 = lane & 15, quad = lane >> 4;
    const int v = blockIdx.x;
    const int j = v >> 3;
    const long tileM = (long)((j / CT) * 8 + (v & 7)) * 128;
    const long tileN = (long)(j % CT) * 128;

    floatx4 acc[4][4];
    #pragma unroll
    for (int i = 0; i < 4; i++)
        #pragma unroll
        for (int jj = 0; jj < 4; jj++) acc[i][jj] = {0.f, 0.f, 0.f, 0.f};

    const int o1 = tid * 16;
    const int r1 = o1 >> 6, c1 = (o1 & 63) >> 1;
    const ushort_t* Ar1 = A + (tileM + r1) * KD + c1;
    const ushort_t* Ar2 = A + (tileM + r1 + 64) * KD + c1;
    const ushort_t* Br1 = Bw + (tileN + r1) * KD + c1;
    const ushort_t* Br2 = Bw + (tileN + r1 + 64) * KD + c1;
    ushort_t* Ad1 = &As[o1 >> 1];
    ushort_t* Ad2 = &As[(o1 >> 1) + 2048];
    ushort_t* Bd1 = &Bs[o1 >> 1];
    ushort_t* Bd2 = &Bs[(o1 >> 1) + 2048];

    for (int k0 = 0; k0 < KD; k0 += 32) {
        async16(Ar1 + k0, Ad1);
        async16(Ar2 + k0, Ad2);
        async16(Br1 + k0, Bd1);
        async16(Br2 + k0, Bd2);
        __syncthreads();
        bf16x8 af[4], bfr[4];
        #pragma unroll
        for (int mi = 0; mi < 4; mi++)
            af[mi] = *(const bf16x8*)&As[(wm * 64 + mi * 16 + l15) * 32 + quad * 8];
        #pragma unroll
        for (int nj = 0; nj < 4; nj++)
            bfr[nj] = *(const bf16x8*)&Bs[(wn * 64 + nj * 16 + l15) * 32 + quad * 8];
        #pragma unroll
        for (int mi = 0; mi < 4; mi++)
            #pragma unroll
            for (int nj = 0; nj < 4; nj++)
                acc[mi][nj] = __builtin_amdgcn_mfma_f32_16x16x32_bf16(af[mi], bfr[nj], acc[mi][nj], 0, 0, 0);
        __syncthreads();
    }

    #pragma unroll
    for (int mi = 0; mi < 4; mi++)
      #pragma unroll
      for (int nj = 0; nj < 4; nj++)
        #pragma unroll
        for (int r = 0; r < 4; r++) {
            long row = tileM + wm * 64 + mi * 16 + quad * 4 + r;
            long col = tileN + wn * 64 + nj * 16 + l15;
            float val = acc[mi][nj][r] + bias[col];
            if (MODE == 0) {
                ((ushort_t*)outp)[row * N_LD + col] = f2bf(val);
            } else if (MODE == 2) {
                float g = 0.5f * val * (1.f + erff(val * 0.70710678118654752f));
                ((ushort_t*)outp)[row * N_LD + col] = f2bf(g);
            } else {  // MODE 4
                float res = bf2f(x1w[row * 256 + col]);
                int orig = win_to_orig((int)row + rowOff);
                ((float*)outp)[(long)orig * 256 + col] = val + res;
            }
        }
}

// ---------- proj GEMM + residual + LN2 (fused, window-linear in & out) ----------
__global__ __launch_bounds__(256, 2) void proj_ln_kernel(
        const ushort_t* __restrict__ A, const ushort_t* __restrict__ Bw,
        const float* __restrict__ pb, const float* __restrict__ x_res,
        const float* __restrict__ n2w, const float* __restrict__ n2b,
        ushort_t* __restrict__ x1w, ushort_t* __restrict__ h2out) {
    __shared__ __align__(16) ushort_t As[64 * 32];     // 4 KB
    __shared__ __align__(16) ushort_t Bs[256 * 32];    // 16 KB
    __shared__ float red_s[4][64];
    __shared__ float red_q[4][64];
    const int tid = threadIdx.x, lane = tid & 63, wid = tid >> 6;
    const int l15 = lane & 15, quad = lane >> 4;
    const long tileM = (long)blockIdx.x * 64;

    floatx4 acc[4][4];
    #pragma unroll
    for (int i = 0; i < 4; i++)
        #pragma unroll
        for (int j = 0; j < 4; j++) acc[i][j] = {0.f, 0.f, 0.f, 0.f};

    const int oA = tid * 16;
    const int rA = oA >> 6, cA = (oA & 63) >> 1;
    const ushort_t* Ap = A + (tileM + rA) * 256 + cA;
    ushort_t* Ad = &As[oA >> 1];

    for (int k0 = 0; k0 < 256; k0 += 32) {
        async16(Ap + k0, Ad);
        #pragma unroll
        for (int ch = 0; ch < 4; ch++) {
            int o = ch * 4096 + oA;
            async16(Bw + (o >> 6) * 256 + ((o & 63) >> 1) + k0, &Bs[o >> 1]);
        }
        __syncthreads();
        bf16x8 af[4], bfr[4];
        #pragma unroll
        for (int mi = 0; mi < 4; mi++)
            af[mi] = *(const bf16x8*)&As[(mi * 16 + l15) * 32 + quad * 8];
        #pragma unroll
        for (int nj = 0; nj < 4; nj++)
            bfr[nj] = *(const bf16x8*)&Bs[(wid * 64 + nj * 16 + l15) * 32 + quad * 8];
        #pragma unroll
        for (int mi = 0; mi < 4; mi++)
            #pragma unroll
            for (int nj = 0; nj < 4; nj++)
                acc[mi][nj] = __builtin_amdgcn_mfma_f32_16x16x32_bf16(af[mi], bfr[nj], acc[mi][nj], 0, 0, 0);
        __syncthreads();
    }

    #pragma unroll
    for (int mi = 0; mi < 4; mi++)
      #pragma unroll
      for (int r = 0; r < 4; r++) {
        int iloc = mi * 16 + quad * 4 + r;
        int orig = win_to_orig((int)tileM + iloc);
        float s = 0.f, q = 0.f;
        #pragma unroll
        for (int nj = 0; nj < 4; nj++) {
            int col = wid * 64 + nj * 16 + l15;
            float val = acc[mi][nj][r] + pb[col] + x_res[(long)orig * 256 + col];
            x1w[(tileM + iloc) * 256 + col] = f2bf(val);
            acc[mi][nj][r] = val;
            s += val; q += val * val;
        }
        #pragma unroll
        for (int d = 1; d < 16; d <<= 1) { s += __shfl_xor(s, d, 64); q += __shfl_xor(q, d, 64); }
        if (l15 == 0) { red_s[wid][iloc] = s; red_q[wid][iloc] = q; }
      }
    __syncthreads();
    #pragma unroll
    for (int mi = 0; mi < 4; mi++)
      #pragma unroll
      for (int r = 0; r < 4; r++) {
        int iloc = mi * 16 + quad * 4 + r;
        float s = red_s[0][iloc] + red_s[1][iloc] + red_s[2][iloc] + red_s[3][iloc];
        float q = red_q[0][iloc] + red_q[1][iloc] + red_q[2][iloc] + red_q[3][iloc];
        float mu = s * 0.00390625f;
        float var = q * 0.00390625f - mu * mu;
        float rstd = rsqrtf(var + 1e-5f);
        #pragma unroll
        for (int nj = 0; nj < 4; nj++) {
            int col = wid * 64 + nj * 16 + l15;
            float val = acc[mi][nj][r];
            h2out[(tileM + iloc) * 256 + col] = f2bf((val - mu) * rstd * n2w[col] + n2b[col]);
        }
      }
}

// ---------- attention: 4 waves/block, P shrunk to 49 rows -> 3 blocks/CU ----------
__global__ __launch_bounds__(256) void attn_kernel(const ushort_t* __restrict__ qkv,
                                                   const ushort_t* __restrict__ bm,
                                                   ushort_t* __restrict__ attnout) {
    __shared__ __align__(16) ushort_t lds[4 * 5832];   // per wave: P[49][72] + Vt[32][72] = 11664 B
    const int tid = threadIdx.x, lane = tid & 63, wid = tid >> 6;
    ushort_t* Pl = &lds[wid * 5832];
    ushort_t* Vt = Pl + 49 * 72;
    const int whid = blockIdx.x * 4 + wid;             // 16384 window-heads
    const int win = whid >> 3, head = whid & 7;
    const int l15 = lane & 15, quad = lane >> 4;
    const long base = (long)win * 49 * 768;
    const ushort_t* bmw = bm + (long)((win & 63) * 8 + head) * 2401;

    // Q (A-frag) and K (B-frag) straight from global
    bf16x8 qf[4], kf[4];
    #pragma unroll
    for (int t4 = 0; t4 < 4; t4++) {
        int tok = t4 * 16 + l15; if (tok > 48) tok = 48;
        const ushort_t* p = qkv + base + (long)tok * 768 + head * 32 + quad * 8;
        qf[t4] = *(const bf16x8*)p;
        kf[t4] = *(const bf16x8*)(p + 256);
    }

    floatx4 S[4][4];
    #pragma unroll
    for (int mi = 0; mi < 4; mi++)
        #pragma unroll
        for (int nj = 0; nj < 4; nj++) {
            floatx4 z = {0.f, 0.f, 0.f, 0.f};
            S[mi][nj] = __builtin_amdgcn_mfma_f32_16x16x32_bf16(qf[mi], kf[nj], z, 0, 0, 0);
        }

    // stage V^T into LDS (stride 72), zero-fill pad cols j>=49
    {
        int jl = lane;
        int jc = jl < 49 ? jl : 48;
        const uint4* vsrc = (const uint4*)(qkv + base + (long)jc * 768 + 512 + head * 32);
        uint4 vz; vz.x = vz.y = vz.z = vz.w = 0u;
        #pragma unroll
        for (int q4 = 0; q4 < 4; q4++) {
            uint4 vv = (jl < 49) ? vsrc[q4] : vz;
            int db = q4 * 8;
            Vt[(db+0)*72 + jl] = (ushort_t)vv.x;  Vt[(db+1)*72 + jl] = (ushort_t)(vv.x >> 16);
            Vt[(db+2)*72 + jl] = (ushort_t)vv.y;  Vt[(db+3)*72 + jl] = (ushort_t)(vv.y >> 16);
            Vt[(db+4)*72 + jl] = (ushort_t)vv.z;  Vt[(db+5)*72 + jl] = (ushort_t)(vv.z >> 16);
            Vt[(db+6)*72 + jl] = (ushort_t)vv.w;  Vt[(db+7)*72 + jl] = (ushort_t)(vv.w >> 16);
        }
    }

    // scale + fused bf16 bias+mask; pad -1e30
    const float scale = 0.17677669529663687f;          // 32^-0.5
    #pragma unroll
    for (int mi = 0; mi < 4; mi++)
      #pragma unroll
      for (int nj = 0; nj < 4; nj++)
        #pragma unroll
        for (int r = 0; r < 4; r++) {
            int i = mi * 16 + quad * 4 + r;
            int jj = nj * 16 + l15;
            float s = -1e30f;
            if (i < 49 && jj < 49) s = S[mi][nj][r] * scale + bf2f(bmw[i * 49 + jj]);
            S[mi][nj][r] = s;
        }

    // row softmax (unnormalized into P; 1/sum folded into output epilogue)
    float rinv[4][4];
    #pragma unroll
    for (int mi = 0; mi < 4; mi++)
      #pragma unroll
      for (int r = 0; r < 4; r++) {
          float m = fmaxf(fmaxf(S[mi][0][r], S[mi][1][r]), fmaxf(S[mi][2][r], S[mi][3][r]));
          #pragma unroll
          for (int d = 1; d < 16; d <<= 1) m = fmaxf(m, __shfl_xor(m, d, 64));
          float e[4], sum = 0.f;
          #pragma unroll
          for (int nj = 0; nj < 4; nj++) { e[nj] = __expf(S[mi][nj][r] - m); sum += e[nj]; }
          #pragma unroll
          for (int d = 1; d < 16; d <<= 1) sum += __shfl_xor(sum, d, 64);
          rinv[mi][r] = 1.f / sum;
          int i = mi * 16 + quad * 4 + r;
          if (i < 49) {
              #pragma unroll
              for (int nj = 0; nj < 4; nj++) Pl[i * 72 + (nj * 16 + l15)] = f2bf(e[nj]);
          }
      }

    __syncthreads();

    floatx4 O[4][2];
    #pragma unroll
    for (int mi = 0; mi < 4; mi++) { O[mi][0] = {0.f,0.f,0.f,0.f}; O[mi][1] = {0.f,0.f,0.f,0.f}; }
    #pragma unroll
    for (int kc = 0; kc < 2; kc++) {
        bf16x8 pf[4], vf[2];
        #pragma unroll
        for (int mi = 0; mi < 4; mi++) {
            int pr = mi * 16 + l15; if (pr > 48) pr = 48;   // rows >=49 unwritten; clamp
            pf[mi] = *(const bf16x8*)&Pl[pr * 72 + kc * 32 + quad * 8];
        }
        #pragma unroll
        for (int n2 = 0; n2 < 2; n2++)
            vf[n2] = *(const bf16x8*)&Vt[(n2 * 16 + l15) * 72 + kc * 32 + quad * 8];
        #pragma unroll
        for (int mi = 0; mi < 4; mi++)
            #pragma unroll
            for (int n2 = 0; n2 < 2; n2++)
                O[mi][n2] = __builtin_amdgcn_mfma_f32_16x16x32_bf16(pf[mi], vf[n2], O[mi][n2], 0, 0, 0);
    }

    #pragma unroll
    for (int mi = 0; mi < 4; mi++)
      #pragma unroll
      for (int n2 = 0; n2 < 2; n2++)
        #pragma unroll
        for (int r = 0; r < 4; r++) {
            int i = mi * 16 + quad * 4 + r;
            if (i < 49) {
                long orow = ((long)win * 49 + i) * 256 + head * 32 + n2 * 16 + l15;
                attnout[orow] = f2bf(O[mi][n2][r] * rinv[mi][r]);
            }
        }
}

// ---------- launcher ----------
extern "C" void kernel_launch(void* const* d_in, const int* in_sizes, int n_in,
                              void* d_out, int out_size, void* d_ws, size_t ws_size,
                              hipStream_t stream) {
    const float* x      = (const float*)d_in[0];
    const float* n1w    = (const float*)d_in[1];
    const float* n1b    = (const float*)d_in[2];
    const float* qkv_w  = (const float*)d_in[3];
    const float* qkv_b  = (const float*)d_in[4];
    const float* rpb    = (const float*)d_in[5];
    const float* proj_w = (const float*)d_in[6];
    const float* proj_b = (const float*)d_in[7];
    const float* n2w    = (const float*)d_in[8];
    const float* n2b    = (const float*)d_in[9];
    const float* fc1_w  = (const float*)d_in[10];
    const float* fc1_b  = (const float*)d_in[11];
    const float* fc2_w  = (const float*)d_in[12];
    const float* fc2_b  = (const float*)d_in[13];
    const int*   rel_idx= (const int*)d_in[14];
    const float* amask  = (const float*)d_in[15];

    // ws layout (peak 207,093,760 B):
    char* ws = (char*)d_ws;
    ushort_t* wq   = (ushort_t*)(ws + 0);          //  393,216 B
    ushort_t* wp   = (ushort_t*)(ws + 393216);     //  131,072 B
    ushort_t* w1   = (ushort_t*)(ws + 524288);     //  524,288 B
    ushort_t* w2   = (ushort_t*)(ws + 1048576);    //  524,288 B
    ushort_t* hwin = (ushort_t*)(ws + 1572864);    // 51,380,224 B (LN1 out; reused attn_out; later h3)
    ushort_t* qkvb = (ushort_t*)(ws + 52953088);   // 154,140,672 B (qkv; reused h2 + x1w)
    ushort_t* h2   = (ushort_t*)(ws + 104333312);  // 51,380,224 B
    ushort_t* x1w  = (ushort_t*)(ws + 155713536);  // 51,380,224 B
    ushort_t* h3   = hwin;                         // 102,760,448 B per half (ends at h2)
    // bm (bf16, 2,458,624 B) lives in d_out scratch — dead after attn, before fc2 writes
    ushort_t* bm = (ushort_t*)d_out;

    convert_kernel<<<4803, 256, 0, stream>>>(qkv_w, proj_w, fc1_w, fc2_w, rpb, rel_idx,
                                             amask, wq, wp, w1, w2, bm);
    ln_kernel<<<TOKS / 4, 256, 0, stream>>>(x, n1w, n1b, hwin);
    // QKV: RT=784, CT=6
    gemm_kernel<0, 768, 256, 6><<<4704, 256, 0, stream>>>(hwin, wq, qkv_b, qkvb, nullptr, 0);
    attn_kernel<<<4096, 256, 0, stream>>>(qkvb, bm, hwin);
    proj_ln_kernel<<<1568, 256, 0, stream>>>(hwin, wp, proj_b, x, n2w, n2b, x1w, h2);
    for (int c = 0; c < 2; c++) {
        // fc1: RT=392, CT=8
        gemm_kernel<2, 1024, 256, 8><<<3136, 256, 0, stream>>>(
            h2 + (long)c * 50176 * 256, w1, fc1_b, h3, nullptr, 0);
        // fc2: RT=392, CT=2
        gemm_kernel<4, 256, 1024, 2><<<784, 256, 0, stream>>>(
            h3, w2, fc2_b, (float*)d_out, x1w + (long)c * 50176 * 256, c * 50176);
    }
    (void)in_sizes; (void)n_in; (void)out_size; (void)ws_size;
}